// Round 1
// baseline (2210.446 us; speedup 1.0000x reference)
//
#include <hip/hip_runtime.h>
#include <hip/hip_bf16.h>
#include <math.h>

#define N_ 8192
#define M_ 4096
#define D_ 512
#define C_ 100

__device__ __forceinline__ float mishf(float v) {
    // softplus stable: log(1+e^v) = max(v,0) + log1p(exp(-|v|))
    float sp = fmaxf(v, 0.f) + log1pf(expf(-fabsf(v)));
    return v * tanhf(sp);
}

// out[r, c] = mish( sum_k A[r,k] * W[k,c] + b[c] ),  A:[R,512] W:[512,512]
// block 256 threads; 64x64 tile; 4x4 micro per thread.
__global__ void gemm_mish(const float* __restrict__ A, const float* __restrict__ W,
                          const float* __restrict__ b, float* __restrict__ out, int R) {
    __shared__ float As[64 * 17];  // [row][k] pad 17
    __shared__ float Ws[16 * 68];  // [k][col] pad 68 (16B-aligned rows)
    const int t  = threadIdx.x;
    const int tx = t & 15, ty = t >> 4;
    const int col0 = blockIdx.x * 64;
    const int row0 = blockIdx.y * 64;

    float acc[4][4] = {};

    for (int k0 = 0; k0 < D_; k0 += 16) {
        __syncthreads();
        // A tile 64x16: one float4 per thread
        {
            int r  = t >> 2;
            int c4 = (t & 3) * 4;
            float4 v = *reinterpret_cast<const float4*>(&A[(size_t)(row0 + r) * D_ + k0 + c4]);
            As[r * 17 + c4 + 0] = v.x; As[r * 17 + c4 + 1] = v.y;
            As[r * 17 + c4 + 2] = v.z; As[r * 17 + c4 + 3] = v.w;
        }
        // W tile 16x64: one float4 per thread
        {
            int r  = t >> 4;
            int c4 = (t & 15) * 4;
            float4 v = *reinterpret_cast<const float4*>(&W[(size_t)(k0 + r) * D_ + col0 + c4]);
            *reinterpret_cast<float4*>(&Ws[r * 68 + c4]) = v;
        }
        __syncthreads();
        #pragma unroll
        for (int kk = 0; kk < 16; ++kk) {
            float a[4];
            #pragma unroll
            for (int i = 0; i < 4; ++i) a[i] = As[(ty * 4 + i) * 17 + kk];
            float4 w = *reinterpret_cast<const float4*>(&Ws[kk * 68 + tx * 4]);
            #pragma unroll
            for (int i = 0; i < 4; ++i) {
                acc[i][0] = fmaf(a[i], w.x, acc[i][0]);
                acc[i][1] = fmaf(a[i], w.y, acc[i][1]);
                acc[i][2] = fmaf(a[i], w.z, acc[i][2]);
                acc[i][3] = fmaf(a[i], w.w, acc[i][3]);
            }
        }
    }

    float4 bv = *reinterpret_cast<const float4*>(&b[col0 + tx * 4]);
    #pragma unroll
    for (int i = 0; i < 4; ++i) {
        int r = row0 + ty * 4 + i;
        float4 o;
        o.x = mishf(acc[i][0] + bv.x);
        o.y = mishf(acc[i][1] + bv.y);
        o.z = mishf(acc[i][2] + bv.z);
        o.w = mishf(acc[i][3] + bv.w);
        *reinterpret_cast<float4*>(&out[(size_t)r * D_ + col0 + tx * 4]) = o;
    }
}

// per-row squared L2 norm of a [R,512] matrix; 1 wave per row, 4 rows/block
__global__ void rownorm2(const float* __restrict__ v, float* __restrict__ out, int R) {
    int w    = threadIdx.x >> 6;
    int lane = threadIdx.x & 63;
    int row  = blockIdx.x * 4 + w;
    if (row >= R) return;
    const float4* p = reinterpret_cast<const float4*>(v + (size_t)row * D_);
    float s = 0.f;
    #pragma unroll
    for (int i = 0; i < 2; ++i) {
        float4 q = p[lane + 64 * i];
        s += q.x * q.x + q.y * q.y + q.z * q.z + q.w * q.w;
    }
    #pragma unroll
    for (int m = 1; m < 64; m <<= 1) s += __shfl_xor(s, m, 64);
    if (lane == 0) out[row] = s;
}

#define FMA4(acc, sc, bv)                  \
    acc.x = fmaf(sc, bv.x, acc.x);         \
    acc.y = fmaf(sc, bv.y, acc.y);         \
    acc.z = fmaf(sc, bv.z, acc.z);         \
    acc.w = fmaf(sc, bv.w, acc.w);

// Fused: dist(n,m) = sqrt(max(|xe_n|^2+|se_m|^2-2 xe_n.se_m,0)); z = tanh(dist@Wp+bp);
// out = log_softmax(z). One block = 32 x-rows, loops over all M anchors.
__global__ void fused_dist_proj(const float* __restrict__ xe, const float* __restrict__ se,
                                const float* __restrict__ xn2, const float* __restrict__ sn2,
                                const float* __restrict__ Wp, const float* __restrict__ bp,
                                float* __restrict__ out) {
    __shared__ float xs[32 * 34];    // kk-major: xs[k*34 + r], 32 rows
    __shared__ float ss[32 * 132];   // kk-major: ss[k*132 + c], 128 cols
    __shared__ float dist[32 * 129]; // [row][col] pad 129

    const int t  = threadIdx.x;
    const int n0 = blockIdx.x * 32;

    // S-phase mapping: rows sr0, sr0+1 ; cols sc0..sc0+3 and sc0+64..sc0+67
    const int sr0 = (t >> 4) * 2;
    const int sc0 = (t & 15) * 4;
    // z-phase mapping: row zr ; col quads at 32*cb + zc0
    const int zr  = t >> 3;
    const int zc0 = (t & 7) * 4;

    const float xnorm0 = xn2[n0 + sr0];
    const float xnorm1 = xn2[n0 + sr0 + 1];

    float4 z4[4];
    #pragma unroll
    for (int i = 0; i < 4; ++i) z4[i] = make_float4(0.f, 0.f, 0.f, 0.f);

    for (int m0 = 0; m0 < M_; m0 += 128) {
        float4 a00 = make_float4(0.f,0.f,0.f,0.f), a01 = a00, a10 = a00, a11 = a00;

        for (int k0 = 0; k0 < D_; k0 += 32) {
            __syncthreads();
            // xe tile: 32 rows x 32 k (transposed into kk-major)
            {
                int row = t >> 3, c4 = (t & 7) * 4;
                float4 v = *reinterpret_cast<const float4*>(&xe[(size_t)(n0 + row) * D_ + k0 + c4]);
                xs[(c4 + 0) * 34 + row] = v.x; xs[(c4 + 1) * 34 + row] = v.y;
                xs[(c4 + 2) * 34 + row] = v.z; xs[(c4 + 3) * 34 + row] = v.w;
            }
            // se tile: 128 rows x 32 k (transposed), 4 float4 per thread
            #pragma unroll
            for (int l = 0; l < 4; ++l) {
                int id = t + l * 256;
                int mrow = id >> 3, c4 = (id & 7) * 4;
                float4 v = *reinterpret_cast<const float4*>(&se[(size_t)(m0 + mrow) * D_ + k0 + c4]);
                ss[(c4 + 0) * 132 + mrow] = v.x; ss[(c4 + 1) * 132 + mrow] = v.y;
                ss[(c4 + 2) * 132 + mrow] = v.z; ss[(c4 + 3) * 132 + mrow] = v.w;
            }
            __syncthreads();
            #pragma unroll
            for (int kk = 0; kk < 32; ++kk) {
                float2 a  = *reinterpret_cast<const float2*>(&xs[kk * 34 + sr0]);
                float4 b0 = *reinterpret_cast<const float4*>(&ss[kk * 132 + sc0]);
                float4 b1 = *reinterpret_cast<const float4*>(&ss[kk * 132 + sc0 + 64]);
                FMA4(a00, a.x, b0); FMA4(a01, a.x, b1);
                FMA4(a10, a.y, b0); FMA4(a11, a.y, b1);
            }
        }

        // dist tile
        float4 sn0 = *reinterpret_cast<const float4*>(&sn2[m0 + sc0]);
        float4 sn1 = *reinterpret_cast<const float4*>(&sn2[m0 + sc0 + 64]);
        {
            const float* s0 = (const float*)&a00; const float* s1 = (const float*)&a01;
            const float* t0 = (const float*)&a10; const float* t1 = (const float*)&a11;
            const float* n0p = (const float*)&sn0; const float* n1p = (const float*)&sn1;
            #pragma unroll
            for (int j = 0; j < 4; ++j) {
                float d;
                d = xnorm0 + n0p[j] - 2.f * s0[j];
                dist[(sr0 + 0) * 129 + sc0 + j]      = sqrtf(fmaxf(d, 0.f));
                d = xnorm0 + n1p[j] - 2.f * s1[j];
                dist[(sr0 + 0) * 129 + sc0 + 64 + j] = sqrtf(fmaxf(d, 0.f));
                d = xnorm1 + n0p[j] - 2.f * t0[j];
                dist[(sr0 + 1) * 129 + sc0 + j]      = sqrtf(fmaxf(d, 0.f));
                d = xnorm1 + n1p[j] - 2.f * t1[j];
                dist[(sr0 + 1) * 129 + sc0 + 64 + j] = sqrtf(fmaxf(d, 0.f));
            }
        }
        __syncthreads();

        // z accumulation: z[zr, 32*cb + zc0 + j] += dist[zr, mm] * Wp[m0+mm, col]
        for (int mm = 0; mm < 128; ++mm) {
            float dv = dist[zr * 129 + mm];
            const float4* wr = reinterpret_cast<const float4*>(Wp + (size_t)(m0 + mm) * C_);
            #pragma unroll
            for (int cb = 0; cb < 4; ++cb) {
                if (cb < 3 || zc0 == 0) {   // col quad fully within C=100
                    float4 w = wr[cb * 8 + (t & 7)];
                    FMA4(z4[cb], dv, w);
                }
            }
        }
        // next m-tile's k-loop starts with __syncthreads(), protecting dist reuse
    }

    // epilogue: bias + tanh + log_softmax over the 100 cols of row (n0+zr)
    float vals[16];
    float lmx = -INFINITY;
    #pragma unroll
    for (int cb = 0; cb < 4; ++cb) {
        const float* zp = (const float*)&z4[cb];
        #pragma unroll
        for (int j = 0; j < 4; ++j) {
            int c = cb * 32 + zc0 + j;
            if (cb < 3 || zc0 == 0) {
                float v = tanhf(zp[j] + bp[c]);
                vals[cb * 4 + j] = v;
                lmx = fmaxf(lmx, v);
            }
        }
    }
    #pragma unroll
    for (int msk = 1; msk < 8; msk <<= 1) lmx = fmaxf(lmx, __shfl_xor(lmx, msk, 64));
    float lsum = 0.f;
    #pragma unroll
    for (int cb = 0; cb < 4; ++cb) {
        #pragma unroll
        for (int j = 0; j < 4; ++j) {
            if (cb < 3 || zc0 == 0) lsum += expf(vals[cb * 4 + j] - lmx);
        }
    }
    #pragma unroll
    for (int msk = 1; msk < 8; msk <<= 1) lsum += __shfl_xor(lsum, msk, 64);
    float lse = lmx + logf(lsum);
    #pragma unroll
    for (int cb = 0; cb < 4; ++cb) {
        #pragma unroll
        for (int j = 0; j < 4; ++j) {
            int c = cb * 32 + zc0 + j;
            if (cb < 3 || zc0 == 0)
                out[(size_t)(n0 + zr) * C_ + c] = vals[cb * 4 + j] - lse;
        }
    }
}

extern "C" void kernel_launch(void* const* d_in, const int* in_sizes, int n_in,
                              void* d_out, int out_size, void* d_ws, size_t ws_size,
                              hipStream_t stream) {
    const float* x       = (const float*)d_in[0];
    const float* samples = (const float*)d_in[1];
    const float* W1      = (const float*)d_in[2];
    const float* b1      = (const float*)d_in[3];
    const float* W2      = (const float*)d_in[4];
    const float* b2      = (const float*)d_in[5];
    const float* Wp      = (const float*)d_in[6];
    const float* bp      = (const float*)d_in[7];
    float* out = (float*)d_out;

    float* ws  = (float*)d_ws;
    float* xe  = ws;                                  // N*512
    float* se  = xe + (size_t)N_ * D_;                // M*512
    float* h   = se + (size_t)M_ * D_;                // N*512 (reused)
    float* xn2 = h + (size_t)N_ * D_;                 // N
    float* sn2 = xn2 + N_;                            // M

    dim3 blk(256);
    // encode x
    gemm_mish<<<dim3(D_ / 64, N_ / 64), blk, 0, stream>>>(x, W1, b1, h, N_);
    gemm_mish<<<dim3(D_ / 64, N_ / 64), blk, 0, stream>>>(h, W2, b2, xe, N_);
    // encode samples
    gemm_mish<<<dim3(D_ / 64, M_ / 64), blk, 0, stream>>>(samples, W1, b1, h, M_);
    gemm_mish<<<dim3(D_ / 64, M_ / 64), blk, 0, stream>>>(h, W2, b2, se, M_);
    // norms
    rownorm2<<<N_ / 4, 256, 0, stream>>>(xe, xn2, N_);
    rownorm2<<<M_ / 4, 256, 0, stream>>>(se, sn2, M_);
    // fused distance + projection + log_softmax
    fused_dist_proj<<<N_ / 32, 256, 0, stream>>>(xe, se, xn2, sn2, Wp, bp, out);
}

// Round 2
// 347.931 us; speedup vs baseline: 6.3531x; 6.3531x over previous
//
#include <hip/hip_runtime.h>
#include <hip/hip_bf16.h>
#include <math.h>

#define N_ 8192
#define M_ 4096
#define D_ 512
#define C_ 100
#define CP_ 112      // C padded to multiple of 16
#define NSPLIT_ 8    // M splits for the fused kernel

typedef _Float16 f16;
typedef f16  f16x8 __attribute__((ext_vector_type(8)));
typedef f16  f16x4 __attribute__((ext_vector_type(4)));
typedef float f32x4 __attribute__((ext_vector_type(4)));

__device__ __forceinline__ float mishf(float v) {
    float sp = fmaxf(v, 0.f) + log1pf(expf(-fabsf(v)));
    return v * tanhf(sp);
}

// ---------------- encoder GEMMs (fp32 VALU, unchanged structure) ----------------
__global__ void gemm_mish(const float* __restrict__ A, const float* __restrict__ W,
                          const float* __restrict__ b, float* __restrict__ out) {
    __shared__ float As[64 * 17];
    __shared__ float Ws[16 * 68];
    const int t  = threadIdx.x;
    const int tx = t & 15, ty = t >> 4;
    const int col0 = blockIdx.x * 64;
    const int row0 = blockIdx.y * 64;
    float acc[4][4] = {};
    for (int k0 = 0; k0 < D_; k0 += 16) {
        __syncthreads();
        {
            int r = t >> 2, c4 = (t & 3) * 4;
            float4 v = *reinterpret_cast<const float4*>(&A[(size_t)(row0 + r) * D_ + k0 + c4]);
            As[r * 17 + c4 + 0] = v.x; As[r * 17 + c4 + 1] = v.y;
            As[r * 17 + c4 + 2] = v.z; As[r * 17 + c4 + 3] = v.w;
        }
        {
            int r = t >> 4, c4 = (t & 15) * 4;
            float4 v = *reinterpret_cast<const float4*>(&W[(size_t)(k0 + r) * D_ + col0 + c4]);
            *reinterpret_cast<float4*>(&Ws[r * 68 + c4]) = v;
        }
        __syncthreads();
        #pragma unroll
        for (int kk = 0; kk < 16; ++kk) {
            float a[4];
            #pragma unroll
            for (int i = 0; i < 4; ++i) a[i] = As[(ty * 4 + i) * 17 + kk];
            float4 w = *reinterpret_cast<const float4*>(&Ws[kk * 68 + tx * 4]);
            #pragma unroll
            for (int i = 0; i < 4; ++i) {
                acc[i][0] = fmaf(a[i], w.x, acc[i][0]);
                acc[i][1] = fmaf(a[i], w.y, acc[i][1]);
                acc[i][2] = fmaf(a[i], w.z, acc[i][2]);
                acc[i][3] = fmaf(a[i], w.w, acc[i][3]);
            }
        }
    }
    float4 bv = *reinterpret_cast<const float4*>(&b[col0 + tx * 4]);
    #pragma unroll
    for (int i = 0; i < 4; ++i) {
        int r = row0 + ty * 4 + i;
        float4 o;
        o.x = mishf(acc[i][0] + bv.x);
        o.y = mishf(acc[i][1] + bv.y);
        o.z = mishf(acc[i][2] + bv.z);
        o.w = mishf(acc[i][3] + bv.w);
        *reinterpret_cast<float4*>(&out[(size_t)r * D_ + col0 + tx * 4]) = o;
    }
}

// layer-2 variant: writes f16 output
__global__ void gemm_mish_f16o(const float* __restrict__ A, const float* __restrict__ W,
                               const float* __restrict__ b, f16* __restrict__ out) {
    __shared__ float As[64 * 17];
    __shared__ float Ws[16 * 68];
    const int t  = threadIdx.x;
    const int tx = t & 15, ty = t >> 4;
    const int col0 = blockIdx.x * 64;
    const int row0 = blockIdx.y * 64;
    float acc[4][4] = {};
    for (int k0 = 0; k0 < D_; k0 += 16) {
        __syncthreads();
        {
            int r = t >> 2, c4 = (t & 3) * 4;
            float4 v = *reinterpret_cast<const float4*>(&A[(size_t)(row0 + r) * D_ + k0 + c4]);
            As[r * 17 + c4 + 0] = v.x; As[r * 17 + c4 + 1] = v.y;
            As[r * 17 + c4 + 2] = v.z; As[r * 17 + c4 + 3] = v.w;
        }
        {
            int r = t >> 4, c4 = (t & 15) * 4;
            float4 v = *reinterpret_cast<const float4*>(&W[(size_t)(k0 + r) * D_ + col0 + c4]);
            *reinterpret_cast<float4*>(&Ws[r * 68 + c4]) = v;
        }
        __syncthreads();
        #pragma unroll
        for (int kk = 0; kk < 16; ++kk) {
            float a[4];
            #pragma unroll
            for (int i = 0; i < 4; ++i) a[i] = As[(ty * 4 + i) * 17 + kk];
            float4 w = *reinterpret_cast<const float4*>(&Ws[kk * 68 + tx * 4]);
            #pragma unroll
            for (int i = 0; i < 4; ++i) {
                acc[i][0] = fmaf(a[i], w.x, acc[i][0]);
                acc[i][1] = fmaf(a[i], w.y, acc[i][1]);
                acc[i][2] = fmaf(a[i], w.z, acc[i][2]);
                acc[i][3] = fmaf(a[i], w.w, acc[i][3]);
            }
        }
    }
    float4 bv = *reinterpret_cast<const float4*>(&b[col0 + tx * 4]);
    #pragma unroll
    for (int i = 0; i < 4; ++i) {
        int r = row0 + ty * 4 + i;
        f16x4 o;
        o[0] = (f16)mishf(acc[i][0] + bv.x);
        o[1] = (f16)mishf(acc[i][1] + bv.y);
        o[2] = (f16)mishf(acc[i][2] + bv.z);
        o[3] = (f16)mishf(acc[i][3] + bv.w);
        *reinterpret_cast<f16x4*>(&out[(size_t)r * D_ + col0 + tx * 4]) = o;
    }
}

// per-row squared L2 norm from f16 matrix [R][512]; 4 rows/block (4 waves)
__global__ void rownorm2_f16(const f16* __restrict__ v, float* __restrict__ out) {
    int w    = threadIdx.x >> 6;
    int lane = threadIdx.x & 63;
    int row  = blockIdx.x * 4 + w;
    f16x8 q = *reinterpret_cast<const f16x8*>(&v[(size_t)row * D_ + lane * 8]);
    float s = 0.f;
    #pragma unroll
    for (int i = 0; i < 8; ++i) { float f = (float)q[i]; s = fmaf(f, f, s); }
    #pragma unroll
    for (int m = 1; m < 64; m <<= 1) s += __shfl_xor(s, m, 64);
    if (lane == 0) out[row] = s;
}

// WpT[c][m] = f16(Wp[m][c]), c padded to 112 with zeros
__global__ void prep_wpT(const float* __restrict__ Wp, f16* __restrict__ WpT) {
    int id = blockIdx.x * 256 + threadIdx.x;   // 112*4096 total
    int c = id >> 12, m = id & 4095;
    float w = (c < C_) ? Wp[(size_t)m * C_ + c] : 0.f;
    WpT[(size_t)c * M_ + m] = (f16)w;
}

// ---------------- fused MFMA kernel ----------------
// block: 128 x-rows (blockIdx.x) x one M-split of 512 anchors (blockIdx.y)
// per 128-anchor tile: S = xe.se^T (MFMA) -> dist f16 in LDS -> z += dist @ WpT (MFMA)
#define LDA 72    // f16 stride for xe/se tiles
#define LDD 136   // f16 stride for dist / wp tiles
__global__ __launch_bounds__(256, 2) void fused_mfma(
        const f16* __restrict__ xe, const f16* __restrict__ se,
        const float* __restrict__ xn2, const float* __restrict__ sn2,
        const f16* __restrict__ WpT, float* __restrict__ zpart) {
    __shared__ char smem[72192];
    f16*   xs = (f16*)smem;               // [128][72]
    f16*   ss = (f16*)(smem + 18432);     // [128][72]
    f16*   wp = (f16*)smem;               // [112][136]  (aliases xs/ss)
    f16*   ds = (f16*)(smem + 36864);     // [128][136]
    float* xn = (float*)(smem + 71680);   // [128]

    const int t    = threadIdx.x;
    const int lane = t & 63;
    const int w    = t >> 6;              // wave 0..3
    const int wr   = w >> 1, wc = w & 1;  // 2x2 wave grid for S
    const int lr   = lane & 15, lk = lane >> 4;

    const int n0    = blockIdx.x * 128;
    const int mbase = blockIdx.y * (M_ / NSPLIT_);

    if (t < 128) xn[t] = xn2[n0 + t];

    f32x4 zacc[2][7];
    #pragma unroll
    for (int i = 0; i < 2; ++i)
        #pragma unroll
        for (int j = 0; j < 7; ++j)
            zacc[i][j] = (f32x4){0.f, 0.f, 0.f, 0.f};

    for (int mt = 0; mt < (M_ / NSPLIT_) / 128; ++mt) {
        const int m0 = mbase + mt * 128;
        f32x4 sacc[4][4];
        #pragma unroll
        for (int i = 0; i < 4; ++i)
            #pragma unroll
            for (int j = 0; j < 4; ++j)
                sacc[i][j] = (f32x4){0.f, 0.f, 0.f, 0.f};

        for (int kc = 0; kc < 8; ++kc) {
            __syncthreads();   // also protects prev z-phase reads before wp region overwrite
            {
                int r = t >> 3, ko = (t & 7) * 8;
                int kg = kc * 64 + ko;
                #pragma unroll
                for (int l = 0; l < 4; ++l) {
                    int row = r + 32 * l;
                    *reinterpret_cast<f16x8*>(&xs[row * LDA + ko]) =
                        *reinterpret_cast<const f16x8*>(&xe[(size_t)(n0 + row) * D_ + kg]);
                    *reinterpret_cast<f16x8*>(&ss[row * LDA + ko]) =
                        *reinterpret_cast<const f16x8*>(&se[(size_t)(m0 + row) * D_ + kg]);
                }
            }
            __syncthreads();
            #pragma unroll
            for (int ks = 0; ks < 2; ++ks) {
                f16x8 af[4], bf[4];
                #pragma unroll
                for (int i = 0; i < 4; ++i) {
                    af[i] = *reinterpret_cast<const f16x8*>(&xs[(wr * 64 + i * 16 + lr) * LDA + ks * 32 + lk * 8]);
                    bf[i] = *reinterpret_cast<const f16x8*>(&ss[(wc * 64 + i * 16 + lr) * LDA + ks * 32 + lk * 8]);
                }
                #pragma unroll
                for (int i = 0; i < 4; ++i)
                    #pragma unroll
                    for (int j = 0; j < 4; ++j)
                        sacc[i][j] = __builtin_amdgcn_mfma_f32_16x16x32_f16(af[i], bf[j], sacc[i][j], 0, 0, 0);
            }
        }
        // dist epilogue: ds[row][m] = sqrt(max(xn+sn-2S,0)) as f16
        {
            float snr[4];
            #pragma unroll
            for (int j = 0; j < 4; ++j) snr[j] = sn2[m0 + wc * 64 + j * 16 + lr];
            #pragma unroll
            for (int i = 0; i < 4; ++i) {
                #pragma unroll
                for (int j = 0; j < 4; ++j) {
                    #pragma unroll
                    for (int q = 0; q < 4; ++q) {
                        int row_l = wr * 64 + i * 16 + lk * 4 + q;
                        int col_l = wc * 64 + j * 16 + lr;
                        float d2 = xn[row_l] + snr[j] - 2.f * sacc[i][j][q];
                        ds[row_l * LDD + col_l] = (f16)sqrtf(fmaxf(d2, 0.f));
                    }
                }
            }
        }
        __syncthreads();           // dist visible; all waves past S reads -> wp staging safe
        // stage WpT tile [112][128]
        #pragma unroll
        for (int l = 0; l < 7; ++l) {
            int id = t + l * 256;
            int c = id >> 4, mo = (id & 15) * 8;
            *reinterpret_cast<f16x8*>(&wp[c * LDD + mo]) =
                *reinterpret_cast<const f16x8*>(&WpT[(size_t)c * M_ + m0 + mo]);
        }
        __syncthreads();
        // z MFMA: wave w handles rows w*32..w*32+31
        #pragma unroll
        for (int ks = 0; ks < 4; ++ks) {
            f16x8 aF0 = *reinterpret_cast<const f16x8*>(&ds[(w * 32 + 0  + lr) * LDD + ks * 32 + lk * 8]);
            f16x8 aF1 = *reinterpret_cast<const f16x8*>(&ds[(w * 32 + 16 + lr) * LDD + ks * 32 + lk * 8]);
            #pragma unroll
            for (int cb = 0; cb < 7; ++cb) {
                f16x8 bF = *reinterpret_cast<const f16x8*>(&wp[(cb * 16 + lr) * LDD + ks * 32 + lk * 8]);
                zacc[0][cb] = __builtin_amdgcn_mfma_f32_16x16x32_f16(aF0, bF, zacc[0][cb], 0, 0, 0);
                zacc[1][cb] = __builtin_amdgcn_mfma_f32_16x16x32_f16(aF1, bF, zacc[1][cb], 0, 0, 0);
            }
        }
    }
    // write partial z
    #pragma unroll
    for (int ar = 0; ar < 2; ++ar) {
        #pragma unroll
        for (int cb = 0; cb < 7; ++cb) {
            #pragma unroll
            for (int q = 0; q < 4; ++q) {
                int row = n0 + w * 32 + ar * 16 + lk * 4 + q;
                int col = cb * 16 + lr;
                zpart[((size_t)blockIdx.y * N_ + row) * CP_ + col] = zacc[ar][cb][q];
            }
        }
    }
}

// reduce splits + bias + tanh + log_softmax; one wave per row
__global__ void z_epilogue(const float* __restrict__ zpart, const float* __restrict__ bp,
                           float* __restrict__ out) {
    const int row  = blockIdx.x;
    const int lane = threadIdx.x;   // 0..63
    float z0 = 0.f, z1 = 0.f;
    #pragma unroll
    for (int s = 0; s < NSPLIT_; ++s) {
        const float* zp = &zpart[((size_t)s * N_ + row) * CP_];
        z0 += zp[lane];
        if (lane + 64 < CP_) z1 += zp[lane + 64];
    }
    float t0 = tanhf(z0 + bp[lane]);                      // lane < 64 < 100: always valid
    bool  v1 = (lane + 64) < C_;
    float t1 = v1 ? tanhf(z1 + bp[lane + 64]) : -INFINITY;
    float mx = fmaxf(t0, t1);
    #pragma unroll
    for (int m = 1; m < 64; m <<= 1) mx = fmaxf(mx, __shfl_xor(mx, m, 64));
    float se_ = expf(t0 - mx) + (v1 ? expf(t1 - mx) : 0.f);
    #pragma unroll
    for (int m = 1; m < 64; m <<= 1) se_ += __shfl_xor(se_, m, 64);
    float lse = mx + logf(se_);
    out[(size_t)row * C_ + lane] = t0 - lse;
    if (v1) out[(size_t)row * C_ + lane + 64] = t1 - lse;
}

extern "C" void kernel_launch(void* const* d_in, const int* in_sizes, int n_in,
                              void* d_out, int out_size, void* d_ws, size_t ws_size,
                              hipStream_t stream) {
    const float* x       = (const float*)d_in[0];
    const float* samples = (const float*)d_in[1];
    const float* W1      = (const float*)d_in[2];
    const float* b1      = (const float*)d_in[3];
    const float* W2      = (const float*)d_in[4];
    const float* b2      = (const float*)d_in[5];
    const float* Wp      = (const float*)d_in[6];
    const float* bp      = (const float*)d_in[7];
    float* out = (float*)d_out;

    char* p = (char*)d_ws;
    float* zpart = (float*)p;                    // 8*8192*112*4 = 29,360,128 B
    float* h     = (float*)p;                    // aliased (dead before zpart written)
    p += (size_t)NSPLIT_ * N_ * CP_ * 4;
    f16* xef = (f16*)p;  p += (size_t)N_ * D_ * 2;
    f16* sef = (f16*)p;  p += (size_t)M_ * D_ * 2;
    float* xn2 = (float*)p; p += (size_t)N_ * 4;
    float* sn2 = (float*)p; p += (size_t)M_ * 4;
    f16* wpT  = (f16*)p;    p += (size_t)CP_ * M_ * 2;

    dim3 blk(256);
    // encoders (layer1 fp32 -> h, layer2 -> f16)
    gemm_mish     <<<dim3(D_ / 64, N_ / 64), blk, 0, stream>>>(x, W1, b1, h);
    gemm_mish_f16o<<<dim3(D_ / 64, N_ / 64), blk, 0, stream>>>(h, W2, b2, xef);
    gemm_mish     <<<dim3(D_ / 64, M_ / 64), blk, 0, stream>>>(samples, W1, b1, h);
    gemm_mish_f16o<<<dim3(D_ / 64, M_ / 64), blk, 0, stream>>>(h, W2, b2, sef);
    // norms from the f16 arrays (consistent with MFMA dot products)
    rownorm2_f16<<<N_ / 4, blk, 0, stream>>>(xef, xn2);
    rownorm2_f16<<<M_ / 4, blk, 0, stream>>>(sef, sn2);
    // Wp transpose/pad/cast
    prep_wpT<<<(CP_ * M_) / 256, blk, 0, stream>>>(Wp, wpT);
    // fused S -> dist -> partial z
    fused_mfma<<<dim3(N_ / 128, NSPLIT_), blk, 0, stream>>>(xef, sef, xn2, sn2, wpT, zpart);
    // reduce + tanh + log_softmax
    z_epilogue<<<N_, 64, 0, stream>>>(zpart, bp, out);
}

// Round 3
// 247.229 us; speedup vs baseline: 8.9409x; 1.4073x over previous
//
#include <hip/hip_runtime.h>
#include <hip/hip_bf16.h>
#include <math.h>

#define N_ 8192
#define M_ 4096
#define D_ 512
#define C_ 100
#define CP_ 112      // C padded to multiple of 16
#define NSPLIT_ 8    // M splits for the fused kernel

typedef _Float16 f16;
typedef f16  f16x8 __attribute__((ext_vector_type(8)));
typedef f16  f16x4 __attribute__((ext_vector_type(4)));
typedef float f32x4 __attribute__((ext_vector_type(4)));

__device__ __forceinline__ float mishf(float v) {
    float sp = fmaxf(v, 0.f) + log1pf(expf(-fabsf(v)));
    return v * tanhf(sp);
}

// ---------------- prep kernels ----------------
__global__ void cast_f16(const float* __restrict__ in, f16* __restrict__ out) {
    int id = blockIdx.x * 256 + threadIdx.x;
    float4 v = reinterpret_cast<const float4*>(in)[id];
    f16x4 o; o[0] = (f16)v.x; o[1] = (f16)v.y; o[2] = (f16)v.z; o[3] = (f16)v.w;
    reinterpret_cast<f16x4*>(out)[id] = o;
}

// WT[c][k] = f16(W[k][c]), 512x512
__global__ void transpose_cast_w(const float* __restrict__ W, f16* __restrict__ WT) {
    __shared__ float ls[64][68];
    const int t = threadIdx.x;
    const int k0 = blockIdx.x * 64, c0 = blockIdx.y * 64;
    {
        int r = t >> 4, c4 = (t & 15) * 4;
        #pragma unroll
        for (int l = 0; l < 4; ++l) {
            int row = r + 16 * l;
            float4 v = *reinterpret_cast<const float4*>(&W[(size_t)(k0 + row) * D_ + c0 + c4]);
            ls[row][c4 + 0] = v.x; ls[row][c4 + 1] = v.y;
            ls[row][c4 + 2] = v.z; ls[row][c4 + 3] = v.w;
        }
    }
    __syncthreads();
    {
        int r = t >> 4, k4 = (t & 15) * 4;
        #pragma unroll
        for (int l = 0; l < 4; ++l) {
            int c = r + 16 * l;
            f16x4 o;
            #pragma unroll
            for (int j = 0; j < 4; ++j) o[j] = (f16)ls[k4 + j][c];
            *reinterpret_cast<f16x4*>(&WT[(size_t)(c0 + c) * D_ + k0 + k4]) = o;
        }
    }
}

// WpT[c][m] = f16(Wp[m][c]), c padded to 112 with zeros
__global__ void prep_wpT(const float* __restrict__ Wp, f16* __restrict__ WpT) {
    int id = blockIdx.x * 256 + threadIdx.x;   // 112*4096 total
    int c = id >> 12, m = id & 4095;
    float w = (c < C_) ? Wp[(size_t)m * C_ + c] : 0.f;
    WpT[(size_t)c * M_ + m] = (f16)w;
}

// per-row squared L2 norm from f16 matrix [R][512]; 4 rows/block
__global__ void rownorm2_f16(const f16* __restrict__ v, float* __restrict__ out) {
    int w    = threadIdx.x >> 6;
    int lane = threadIdx.x & 63;
    int row  = blockIdx.x * 4 + w;
    f16x8 q = *reinterpret_cast<const f16x8*>(&v[(size_t)row * D_ + lane * 8]);
    float s = 0.f;
    #pragma unroll
    for (int i = 0; i < 8; ++i) { float f = (float)q[i]; s = fmaf(f, f, s); }
    #pragma unroll
    for (int m = 1; m < 64; m <<= 1) s += __shfl_xor(s, m, 64);
    if (lane == 0) out[row] = s;
}

// ---------------- encoder GEMM on MFMA ----------------
// out[r,c] = f16(mish(sum_k A[r,k]*WT[c,k] + b[c])), A:[R,512] f16, WT:[512,512] f16
// 128x128 tile, 4 waves (2x2), each wave 64x64 (4x4 frags of 16x16x32).
#define LDA 72
__global__ __launch_bounds__(256) void gemm_mish_mfma(
        const f16* __restrict__ A, const f16* __restrict__ WT,
        const float* __restrict__ b, f16* __restrict__ out) {
    __shared__ char smem[36864];
    f16* as_ = (f16*)smem;              // [128][72]
    f16* ws_ = (f16*)(smem + 18432);    // [128][72]
    f16* os_ = (f16*)smem;              // [128][136] output staging (alias)

    const int t    = threadIdx.x;
    const int lane = t & 63;
    const int w    = t >> 6;
    const int wr   = w >> 1, wc = w & 1;
    const int lr   = lane & 15, lk = lane >> 4;
    const int c0   = blockIdx.x * 128;
    const int n0   = blockIdx.y * 128;

    f32x4 sacc[4][4];
    #pragma unroll
    for (int i = 0; i < 4; ++i)
        #pragma unroll
        for (int j = 0; j < 4; ++j)
            sacc[i][j] = (f32x4){0.f, 0.f, 0.f, 0.f};

    for (int kc = 0; kc < 8; ++kc) {
        __syncthreads();
        {
            int r = t >> 3, ko = (t & 7) * 8;
            int kg = kc * 64 + ko;
            #pragma unroll
            for (int l = 0; l < 4; ++l) {
                int row = r + 32 * l;
                *reinterpret_cast<f16x8*>(&as_[row * LDA + ko]) =
                    *reinterpret_cast<const f16x8*>(&A[(size_t)(n0 + row) * D_ + kg]);
                *reinterpret_cast<f16x8*>(&ws_[row * LDA + ko]) =
                    *reinterpret_cast<const f16x8*>(&WT[(size_t)(c0 + row) * D_ + kg]);
            }
        }
        __syncthreads();
        #pragma unroll
        for (int ks = 0; ks < 2; ++ks) {
            f16x8 af[4], bf[4];
            #pragma unroll
            for (int i = 0; i < 4; ++i) {
                af[i] = *reinterpret_cast<const f16x8*>(&as_[(wr * 64 + i * 16 + lr) * LDA + ks * 32 + lk * 8]);
                bf[i] = *reinterpret_cast<const f16x8*>(&ws_[(wc * 64 + i * 16 + lr) * LDA + ks * 32 + lk * 8]);
            }
            #pragma unroll
            for (int i = 0; i < 4; ++i)
                #pragma unroll
                for (int j = 0; j < 4; ++j)
                    sacc[i][j] = __builtin_amdgcn_mfma_f32_16x16x32_f16(af[i], bf[j], sacc[i][j], 0, 0, 0);
        }
    }
    __syncthreads();   // all waves done reading as_/ws_ before aliasing with os_
    {
        float bv[4];
        #pragma unroll
        for (int j = 0; j < 4; ++j) bv[j] = b[c0 + wc * 64 + j * 16 + lr];
        #pragma unroll
        for (int i = 0; i < 4; ++i)
            #pragma unroll
            for (int j = 0; j < 4; ++j)
                #pragma unroll
                for (int q = 0; q < 4; ++q) {
                    int row_l = wr * 64 + i * 16 + lk * 4 + q;
                    int col_l = wc * 64 + j * 16 + lr;
                    os_[row_l * 136 + col_l] = (f16)mishf(sacc[i][j][q] + bv[j]);
                }
    }
    __syncthreads();
    #pragma unroll
    for (int l = 0; l < 8; ++l) {
        int id = t + l * 256;
        int row = id >> 4, co = (id & 15) * 8;
        *reinterpret_cast<f16x8*>(&out[(size_t)(n0 + row) * D_ + c0 + co]) =
            *reinterpret_cast<const f16x8*>(&os_[row * 136 + co]);
    }
}

// ---------------- fused distance + projection (MFMA) ----------------
#define LDD 136
__global__ __launch_bounds__(256, 2) void fused_mfma(
        const f16* __restrict__ xe, const f16* __restrict__ se,
        const float* __restrict__ xn2, const float* __restrict__ sn2,
        const f16* __restrict__ WpT, float* __restrict__ zpart) {
    __shared__ char smem[72192];
    f16*   xs = (f16*)smem;               // [128][72]
    f16*   ss = (f16*)(smem + 18432);     // [128][72]
    f16*   wp = (f16*)smem;               // [112][136]  (aliases xs/ss)
    f16*   ds = (f16*)(smem + 36864);     // [128][136]
    float* xn = (float*)(smem + 71680);   // [128]

    const int t    = threadIdx.x;
    const int lane = t & 63;
    const int w    = t >> 6;
    const int wr   = w >> 1, wc = w & 1;
    const int lr   = lane & 15, lk = lane >> 4;

    const int n0    = blockIdx.x * 128;
    const int mbase = blockIdx.y * (M_ / NSPLIT_);

    if (t < 128) xn[t] = xn2[n0 + t];

    f32x4 zacc[2][7];
    #pragma unroll
    for (int i = 0; i < 2; ++i)
        #pragma unroll
        for (int j = 0; j < 7; ++j)
            zacc[i][j] = (f32x4){0.f, 0.f, 0.f, 0.f};

    for (int mt = 0; mt < (M_ / NSPLIT_) / 128; ++mt) {
        const int m0 = mbase + mt * 128;
        f32x4 sacc[4][4];
        #pragma unroll
        for (int i = 0; i < 4; ++i)
            #pragma unroll
            for (int j = 0; j < 4; ++j)
                sacc[i][j] = (f32x4){0.f, 0.f, 0.f, 0.f};

        for (int kc = 0; kc < 8; ++kc) {
            __syncthreads();
            {
                int r = t >> 3, ko = (t & 7) * 8;
                int kg = kc * 64 + ko;
                #pragma unroll
                for (int l = 0; l < 4; ++l) {
                    int row = r + 32 * l;
                    *reinterpret_cast<f16x8*>(&xs[row * LDA + ko]) =
                        *reinterpret_cast<const f16x8*>(&xe[(size_t)(n0 + row) * D_ + kg]);
                    *reinterpret_cast<f16x8*>(&ss[row * LDA + ko]) =
                        *reinterpret_cast<const f16x8*>(&se[(size_t)(m0 + row) * D_ + kg]);
                }
            }
            __syncthreads();
            #pragma unroll
            for (int ks = 0; ks < 2; ++ks) {
                f16x8 af[4], bf[4];
                #pragma unroll
                for (int i = 0; i < 4; ++i) {
                    af[i] = *reinterpret_cast<const f16x8*>(&xs[(wr * 64 + i * 16 + lr) * LDA + ks * 32 + lk * 8]);
                    bf[i] = *reinterpret_cast<const f16x8*>(&ss[(wc * 64 + i * 16 + lr) * LDA + ks * 32 + lk * 8]);
                }
                #pragma unroll
                for (int i = 0; i < 4; ++i)
                    #pragma unroll
                    for (int j = 0; j < 4; ++j)
                        sacc[i][j] = __builtin_amdgcn_mfma_f32_16x16x32_f16(af[i], bf[j], sacc[i][j], 0, 0, 0);
            }
        }
        {
            float snr[4];
            #pragma unroll
            for (int j = 0; j < 4; ++j) snr[j] = sn2[m0 + wc * 64 + j * 16 + lr];
            #pragma unroll
            for (int i = 0; i < 4; ++i) {
                #pragma unroll
                for (int j = 0; j < 4; ++j) {
                    #pragma unroll
                    for (int q = 0; q < 4; ++q) {
                        int row_l = wr * 64 + i * 16 + lk * 4 + q;
                        int col_l = wc * 64 + j * 16 + lr;
                        float d2 = xn[row_l] + snr[j] - 2.f * sacc[i][j][q];
                        ds[row_l * LDD + col_l] = (f16)sqrtf(fmaxf(d2, 0.f));
                    }
                }
            }
        }
        __syncthreads();
        #pragma unroll
        for (int l = 0; l < 7; ++l) {
            int id = t + l * 256;
            int c = id >> 4, mo = (id & 15) * 8;
            *reinterpret_cast<f16x8*>(&wp[c * LDD + mo]) =
                *reinterpret_cast<const f16x8*>(&WpT[(size_t)c * M_ + m0 + mo]);
        }
        __syncthreads();
        #pragma unroll
        for (int ks = 0; ks < 4; ++ks) {
            f16x8 aF0 = *reinterpret_cast<const f16x8*>(&ds[(w * 32 + 0  + lr) * LDD + ks * 32 + lk * 8]);
            f16x8 aF1 = *reinterpret_cast<const f16x8*>(&ds[(w * 32 + 16 + lr) * LDD + ks * 32 + lk * 8]);
            #pragma unroll
            for (int cb = 0; cb < 7; ++cb) {
                f16x8 bF = *reinterpret_cast<const f16x8*>(&wp[(cb * 16 + lr) * LDD + ks * 32 + lk * 8]);
                zacc[0][cb] = __builtin_amdgcn_mfma_f32_16x16x32_f16(aF0, bF, zacc[0][cb], 0, 0, 0);
                zacc[1][cb] = __builtin_amdgcn_mfma_f32_16x16x32_f16(aF1, bF, zacc[1][cb], 0, 0, 0);
            }
        }
    }
    #pragma unroll
    for (int ar = 0; ar < 2; ++ar) {
        #pragma unroll
        for (int cb = 0; cb < 7; ++cb) {
            #pragma unroll
            for (int q = 0; q < 4; ++q) {
                int row = n0 + w * 32 + ar * 16 + lk * 4 + q;
                int col = cb * 16 + lr;
                zpart[((size_t)blockIdx.y * N_ + row) * CP_ + col] = zacc[ar][cb][q];
            }
        }
    }
}

// reduce splits + bias + tanh + log_softmax; one wave per row
__global__ void z_epilogue(const float* __restrict__ zpart, const float* __restrict__ bp,
                           float* __restrict__ out) {
    const int row  = blockIdx.x;
    const int lane = threadIdx.x;   // 0..63
    float z0 = 0.f, z1 = 0.f;
    #pragma unroll
    for (int s = 0; s < NSPLIT_; ++s) {
        const float* zp = &zpart[((size_t)s * N_ + row) * CP_];
        z0 += zp[lane];
        if (lane + 64 < CP_) z1 += zp[lane + 64];
    }
    float t0 = tanhf(z0 + bp[lane]);
    bool  v1 = (lane + 64) < C_;
    float t1 = v1 ? tanhf(z1 + bp[lane + 64]) : -INFINITY;
    float mx = fmaxf(t0, t1);
    #pragma unroll
    for (int m = 1; m < 64; m <<= 1) mx = fmaxf(mx, __shfl_xor(mx, m, 64));
    float se_ = expf(t0 - mx) + (v1 ? expf(t1 - mx) : 0.f);
    #pragma unroll
    for (int m = 1; m < 64; m <<= 1) se_ += __shfl_xor(se_, m, 64);
    float lse = mx + logf(se_);
    out[(size_t)row * C_ + lane] = t0 - lse;
    if (v1) out[(size_t)row * C_ + lane + 64] = t1 - lse;
}

extern "C" void kernel_launch(void* const* d_in, const int* in_sizes, int n_in,
                              void* d_out, int out_size, void* d_ws, size_t ws_size,
                              hipStream_t stream) {
    const float* x       = (const float*)d_in[0];
    const float* samples = (const float*)d_in[1];
    const float* W1      = (const float*)d_in[2];
    const float* b1      = (const float*)d_in[3];
    const float* W2      = (const float*)d_in[4];
    const float* b2      = (const float*)d_in[5];
    const float* Wp      = (const float*)d_in[6];
    const float* bp      = (const float*)d_in[7];
    float* out = (float*)d_out;

    char* p = (char*)d_ws;
    float* zpart = (float*)p;                      // 8*8192*112*4 = 29,360,128 B
    // aliases inside the zpart region (all dead before fused_mfma writes zpart):
    f16* h_x = (f16*)p;                            // 8,388,608 B
    f16* h_s = (f16*)(p + 8388608);                // 4,194,304 B
    f16* xh  = (f16*)(p + 12582912);               // 8,388,608 B
    f16* sh  = (f16*)(p + 20971520);               // 4,194,304 B
    f16* w1t = (f16*)(p + 25165824);               //   524,288 B
    f16* w2t = (f16*)(p + 25690112);               //   524,288 B (ends at 26,214,400)
    p += (size_t)NSPLIT_ * N_ * CP_ * 4;
    f16* xef = (f16*)p;    p += (size_t)N_ * D_ * 2;
    f16* sef = (f16*)p;    p += (size_t)M_ * D_ * 2;
    float* xn2 = (float*)p; p += (size_t)N_ * 4;
    float* sn2 = (float*)p; p += (size_t)M_ * 4;
    f16* wpT = (f16*)p;     p += (size_t)CP_ * M_ * 2;

    dim3 blk(256);
    // prep: casts + weight transposes
    cast_f16<<<(N_ * D_) / 1024, blk, 0, stream>>>(x, xh);
    cast_f16<<<(M_ * D_) / 1024, blk, 0, stream>>>(samples, sh);
    transpose_cast_w<<<dim3(8, 8), blk, 0, stream>>>(W1, w1t);
    transpose_cast_w<<<dim3(8, 8), blk, 0, stream>>>(W2, w2t);
    // encoders on MFMA
    gemm_mish_mfma<<<dim3(4, N_ / 128), blk, 0, stream>>>(xh,  w1t, b1, h_x);
    gemm_mish_mfma<<<dim3(4, N_ / 128), blk, 0, stream>>>(h_x, w2t, b2, xef);
    gemm_mish_mfma<<<dim3(4, M_ / 128), blk, 0, stream>>>(sh,  w1t, b1, h_s);
    gemm_mish_mfma<<<dim3(4, M_ / 128), blk, 0, stream>>>(h_s, w2t, b2, sef);
    // norms from the f16 arrays (consistent with MFMA dot products)
    rownorm2_f16<<<N_ / 4, blk, 0, stream>>>(xef, xn2);
    rownorm2_f16<<<M_ / 4, blk, 0, stream>>>(sef, sn2);
    // Wp transpose/pad/cast
    prep_wpT<<<(CP_ * M_) / 256, blk, 0, stream>>>(Wp, wpT);
    // fused S -> dist -> partial z
    fused_mfma<<<dim3(N_ / 128, NSPLIT_), blk, 0, stream>>>(xef, sef, xn2, sn2, wpT, zpart);
    // reduce + tanh + log_softmax
    z_epilogue<<<N_, 64, 0, stream>>>(zpart, bp, out);
}

// Round 4
// 234.732 us; speedup vs baseline: 9.4169x; 1.0532x over previous
//
#include <hip/hip_runtime.h>
#include <hip/hip_bf16.h>
#include <math.h>

#define N_ 8192
#define M_ 4096
#define R_ 12288          // N_ + M_
#define D_ 512
#define C_ 100
#define CP_ 112
#define NSPLIT_ 8

typedef _Float16 f16;
typedef f16  f16x8 __attribute__((ext_vector_type(8)));
typedef f16  f16x4 __attribute__((ext_vector_type(4)));
typedef float f32x4 __attribute__((ext_vector_type(4)));

__device__ __forceinline__ float mishf(float v) {
    float sp = fmaxf(v, 0.f) + log1pf(expf(-fabsf(v)));
    return v * tanhf(sp);
}

// async global->LDS, 16B per lane; LDS dest = wave-uniform base + lane*16
__device__ __forceinline__ void gll16(const void* g, void* l) {
    __builtin_amdgcn_global_load_lds(
        (const __attribute__((address_space(1))) unsigned int*)g,
        (__attribute__((address_space(3))) unsigned int*)l, 16, 0, 0);
}

// ---------------- prep: casts + W1/W2 transpose + WpT (one launch) ----------------
__global__ void prep_all(const float* __restrict__ x, const float* __restrict__ samples,
                         const float* __restrict__ W1, const float* __restrict__ W2,
                         const float* __restrict__ Wp,
                         f16* __restrict__ xsh, f16* __restrict__ w1t,
                         f16* __restrict__ w2t, f16* __restrict__ wpT) {
    const int bid = blockIdx.x, t = threadIdx.x;
    if (bid < 1536) {
        const float4* x4 = (const float4*)x;
        const float4* s4 = (const float4*)samples;
        f16x4* o4 = (f16x4*)xsh;
        for (int fid = bid * 256 + t; fid < (R_ * D_ / 4); fid += 1536 * 256) {
            float4 v = (fid < N_ * D_ / 4) ? x4[fid] : s4[fid - N_ * D_ / 4];
            f16x4 o; o[0] = (f16)v.x; o[1] = (f16)v.y; o[2] = (f16)v.z; o[3] = (f16)v.w;
            o4[fid] = o;
        }
    } else if (bid < 1792) {
        int b = bid - 1536;
        for (int eid = b * 256 + t; eid < 2 * D_ * D_; eid += 256 * 256) {
            int which = eid >= D_ * D_;
            int e = eid - which * D_ * D_;
            int k = e & 511, c = e >> 9;
            const float* W = which ? W2 : W1;
            f16* WT = which ? w2t : w1t;
            WT[(size_t)c * D_ + k] = (f16)W[(size_t)k * D_ + c];
        }
    } else {
        int b = bid - 1792;
        for (int eid = b * 256 + t; eid < CP_ * M_; eid += 256 * 256) {
            int m = eid & 4095, c = eid >> 12;
            float v = (c < C_) ? Wp[(size_t)m * C_ + c] : 0.f;
            wpT[(size_t)c * M_ + m] = (f16)v;
        }
    }
}

// ---------------- encoder GEMM + mish on MFMA ----------------
// out[r,c] = f16(mish(sum_k A[r,k]*WT[c,k] + b[c])); optional per-colblock row-norm partials.
// 128x128 tile, 4 waves (2x2). LDS tiles [128][64]f16 linear, XOR-swizzled 16B chunks.
template<bool NORMS>
__global__ __launch_bounds__(256) void enc_mfma(
        const f16* __restrict__ A, const f16* __restrict__ WT,
        const float* __restrict__ b, f16* __restrict__ out,
        float* __restrict__ np8) {
    __shared__ char smem[32768];
    char* xs = smem;            // [128] rows * 128B (swizzled chunks)
    char* ws = smem + 16384;
    char* os = smem;            // [128] rows * 256B f16 output staging (aliases)

    const int t = threadIdx.x;
    const int lane = t & 63;
    const int w  = t >> 6;
    const int wr = w >> 1, wc = w & 1;
    const int lr = lane & 15, lk = lane >> 4;
    const int c0 = blockIdx.x * 128;
    const int n0 = blockIdx.y * 128;

    const int sub  = lane >> 3;          // row within 8-row group
    const int cswz = (lane & 7) ^ sub;   // pre-swizzled source chunk
    const char* gA = (const char*)(A  + (size_t)(n0 + w * 32 + sub) * D_) + cswz * 16;
    const char* gW = (const char*)(WT + (size_t)(c0 + w * 32 + sub) * D_) + cswz * 16;
    char* lA = xs + (w * 32) * 128;
    char* lW = ws + (w * 32) * 128;

    f32x4 acc[4][4];
    #pragma unroll
    for (int i = 0; i < 4; ++i)
        #pragma unroll
        for (int j = 0; j < 4; ++j) acc[i][j] = (f32x4){0.f, 0.f, 0.f, 0.f};

    for (int kc = 0; kc < 8; ++kc) {
        __syncthreads();
        #pragma unroll
        for (int s = 0; s < 4; ++s) {
            gll16(gA + kc * 128 + s * 8192, lA + s * 1024);
            gll16(gW + kc * 128 + s * 8192, lW + s * 1024);
        }
        __syncthreads();   // drains vmcnt, then barrier: tiles complete
        #pragma unroll
        for (int ks = 0; ks < 2; ++ks) {
            f16x8 af[4], bf[4];
            const int csw = (ks * 4 + lk) ^ (lr & 7);
            #pragma unroll
            for (int i = 0; i < 4; ++i) {
                af[i] = *(const f16x8*)(xs + (wr * 64 + i * 16 + lr) * 128 + csw * 16);
                bf[i] = *(const f16x8*)(ws + (wc * 64 + i * 16 + lr) * 128 + csw * 16);
            }
            #pragma unroll
            for (int i = 0; i < 4; ++i)
                #pragma unroll
                for (int j = 0; j < 4; ++j)
                    acc[i][j] = __builtin_amdgcn_mfma_f32_16x16x32_f16(af[i], bf[j], acc[i][j], 0, 0, 0);
        }
    }
    __syncthreads();   // xs/ws reads done before os alias
    {
        float bv[4];
        #pragma unroll
        for (int j = 0; j < 4; ++j) bv[j] = b[c0 + wc * 64 + j * 16 + lr];
        float rn[4][4] = {};
        #pragma unroll
        for (int i = 0; i < 4; ++i)
            #pragma unroll
            for (int j = 0; j < 4; ++j)
                #pragma unroll
                for (int q = 0; q < 4; ++q) {
                    float v = mishf(acc[i][j][q] + bv[j]);
                    f16 h = (f16)v;
                    int row_l = wr * 64 + i * 16 + lk * 4 + q;
                    int col_l = wc * 64 + j * 16 + lr;
                    *(f16*)(os + row_l * 256 + (((col_l >> 3) ^ (row_l & 7)) * 16) + (col_l & 7) * 2) = h;
                    if (NORMS) { float fv = (float)h; rn[i][q] = fmaf(fv, fv, rn[i][q]); }
                }
        if (NORMS) {
            #pragma unroll
            for (int i = 0; i < 4; ++i)
                #pragma unroll
                for (int q = 0; q < 4; ++q) {
                    float s = rn[i][q];
                    s += __shfl_xor(s, 1, 64); s += __shfl_xor(s, 2, 64);
                    s += __shfl_xor(s, 4, 64); s += __shfl_xor(s, 8, 64);
                    if (lr == 0)
                        np8[(size_t)(blockIdx.x * 2 + wc) * R_ + n0 + wr * 64 + i * 16 + lk * 4 + q] = s;
                }
        }
    }
    __syncthreads();
    #pragma unroll
    for (int l2 = 0; l2 < 8; ++l2) {
        int id = t + l2 * 256;
        int row = id >> 4, cc = id & 15;
        f16x8 v = *(const f16x8*)(os + row * 256 + ((cc ^ (row & 7)) * 16));
        *(f16x8*)(out + (size_t)(n0 + row) * D_ + c0 + cc * 8) = v;
    }
}

// ---------------- fused distance + projection (MFMA) ----------------
// ef: [12288][512] f16 (xe rows 0..8191, se rows 8192..); np8: [8][12288] norm partials
__global__ __launch_bounds__(256) void fused_mfma(
        const f16* __restrict__ ef, const float* __restrict__ np8,
        const f16* __restrict__ WpT, float* __restrict__ zpart) {
    __shared__ char smem[66560];
    char* xs = smem;                      // 16 KB
    char* ss = smem + 16384;              // 16 KB
    char* wp = smem;                      // 28 KB (aliases xs/ss, staged after S-phase)
    char* ds = smem + 32768;              // 32 KB dist tile [128] rows * 256B
    float* xn  = (float*)(smem + 65536);  // [128]
    float* snl = (float*)(smem + 66048);  // [128]

    const int t = threadIdx.x, lane = t & 63, w = t >> 6;
    const int wr = w >> 1, wc = w & 1, lr = lane & 15, lk = lane >> 4;
    const int n0 = blockIdx.x * 128;
    const int mbase = blockIdx.y * (M_ / NSPLIT_);

    const int sub  = lane >> 3;
    const int cswz = (lane & 7) ^ sub;
    const char* gX = (const char*)(ef + (size_t)(n0 + w * 32 + sub) * D_) + cswz * 16;
    char* lX = xs + (w * 32) * 128;
    char* lS = ss + (w * 32) * 128;
    const int wsub = lane >> 4;   // wp staging: row within 4-row group

    if (t < 128) {
        float s = 0.f;
        #pragma unroll
        for (int p = 0; p < 8; ++p) s += np8[(size_t)p * R_ + n0 + t];
        xn[t] = s;
    }

    f32x4 zacc[2][7];
    #pragma unroll
    for (int i = 0; i < 2; ++i)
        #pragma unroll
        for (int j = 0; j < 7; ++j) zacc[i][j] = (f32x4){0.f, 0.f, 0.f, 0.f};

    for (int mt = 0; mt < (M_ / NSPLIT_) / 128; ++mt) {
        const int m0 = mbase + mt * 128;
        const char* gS = (const char*)(ef + (size_t)(N_ + m0 + w * 32 + sub) * D_) + cswz * 16;

        f32x4 sacc[4][4];
        #pragma unroll
        for (int i = 0; i < 4; ++i)
            #pragma unroll
            for (int j = 0; j < 4; ++j) sacc[i][j] = (f32x4){0.f, 0.f, 0.f, 0.f};

        for (int kc = 0; kc < 8; ++kc) {
            __syncthreads();   // prev readers of xs/ss (incl. z-phase wp reads) done
            #pragma unroll
            for (int s = 0; s < 4; ++s) {
                gll16(gX + kc * 128 + s * 8192, lX + s * 1024);
                gll16(gS + kc * 128 + s * 8192, lS + s * 1024);
            }
            if (kc == 0 && t < 128) {
                float s2 = 0.f;
                #pragma unroll
                for (int p = 0; p < 8; ++p) s2 += np8[(size_t)p * R_ + N_ + m0 + t];
                snl[t] = s2;
            }
            __syncthreads();
            #pragma unroll
            for (int ks = 0; ks < 2; ++ks) {
                f16x8 af[4], bf[4];
                const int csw = (ks * 4 + lk) ^ (lr & 7);
                #pragma unroll
                for (int i = 0; i < 4; ++i) {
                    af[i] = *(const f16x8*)(xs + (wr * 64 + i * 16 + lr) * 128 + csw * 16);
                    bf[i] = *(const f16x8*)(ss + (wc * 64 + i * 16 + lr) * 128 + csw * 16);
                }
                #pragma unroll
                for (int i = 0; i < 4; ++i)
                    #pragma unroll
                    for (int j = 0; j < 4; ++j)
                        sacc[i][j] = __builtin_amdgcn_mfma_f32_16x16x32_f16(af[i], bf[j], sacc[i][j], 0, 0, 0);
            }
        }
        // dist epilogue -> ds (f16, swizzled)
        #pragma unroll
        for (int i = 0; i < 4; ++i)
            #pragma unroll
            for (int j = 0; j < 4; ++j)
                #pragma unroll
                for (int q = 0; q < 4; ++q) {
                    int row_l = wr * 64 + i * 16 + lk * 4 + q;
                    int col_l = wc * 64 + j * 16 + lr;
                    float d2 = xn[row_l] + snl[col_l] - 2.f * sacc[i][j][q];
                    *(f16*)(ds + row_l * 256 + (((col_l >> 3) ^ (row_l & 7)) * 16) + (col_l & 7) * 2)
                        = (f16)sqrtf(fmaxf(d2, 0.f));
                }
        __syncthreads();   // S reads done -> wp may overwrite xs/ss; ds visible
        #pragma unroll
        for (int s = 0; s < 7; ++s) {
            int row = w * 28 + s * 4 + wsub;
            int cs  = (lane & 15) ^ (row & 7);
            gll16((const char*)WpT + (size_t)row * (M_ * 2) + (size_t)m0 * 2 + cs * 16,
                  wp + (w * 28 + s * 4) * 256);
        }
        __syncthreads();
        // z MFMA: wave w rows w*32..w*32+31; K = 128 anchors
        #pragma unroll
        for (int ks = 0; ks < 4; ++ks) {
            const int csw = (ks * 4 + lk) ^ (lr & 7);
            f16x8 aF0 = *(const f16x8*)(ds + (w * 32 + 0  + lr) * 256 + csw * 16);
            f16x8 aF1 = *(const f16x8*)(ds + (w * 32 + 16 + lr) * 256 + csw * 16);
            #pragma unroll
            for (int cb = 0; cb < 7; ++cb) {
                f16x8 bF = *(const f16x8*)(wp + (cb * 16 + lr) * 256 + csw * 16);
                zacc[0][cb] = __builtin_amdgcn_mfma_f32_16x16x32_f16(aF0, bF, zacc[0][cb], 0, 0, 0);
                zacc[1][cb] = __builtin_amdgcn_mfma_f32_16x16x32_f16(aF1, bF, zacc[1][cb], 0, 0, 0);
            }
        }
    }
    #pragma unroll
    for (int ar = 0; ar < 2; ++ar)
        #pragma unroll
        for (int cb = 0; cb < 7; ++cb)
            #pragma unroll
            for (int q = 0; q < 4; ++q) {
                int row = n0 + w * 32 + ar * 16 + lk * 4 + q;
                int col = cb * 16 + lr;
                zpart[((size_t)blockIdx.y * N_ + row) * CP_ + col] = zacc[ar][cb][q];
            }
}

// reduce splits + bias + tanh + log_softmax; 4 rows per 256-thread block
__global__ void z_epilogue(const float* __restrict__ zpart, const float* __restrict__ bp,
                           float* __restrict__ out) {
    const int w = threadIdx.x >> 6, lane = threadIdx.x & 63;
    const int row = blockIdx.x * 4 + w;
    float z0 = 0.f, z1 = 0.f;
    #pragma unroll
    for (int s = 0; s < NSPLIT_; ++s) {
        const float* zp = &zpart[((size_t)s * N_ + row) * CP_];
        z0 += zp[lane];
        if (lane + 64 < CP_) z1 += zp[lane + 64];
    }
    float t0 = tanhf(z0 + bp[lane]);
    bool  v1 = (lane + 64) < C_;
    float t1 = v1 ? tanhf(z1 + bp[lane + 64]) : -INFINITY;
    float mx = fmaxf(t0, t1);
    #pragma unroll
    for (int m = 1; m < 64; m <<= 1) mx = fmaxf(mx, __shfl_xor(mx, m, 64));
    float se_ = expf(t0 - mx) + (v1 ? expf(t1 - mx) : 0.f);
    #pragma unroll
    for (int m = 1; m < 64; m <<= 1) se_ += __shfl_xor(se_, m, 64);
    float lse = mx + logf(se_);
    out[(size_t)row * C_ + lane] = t0 - lse;
    if (v1) out[(size_t)row * C_ + lane + 64] = t1 - lse;
}

extern "C" void kernel_launch(void* const* d_in, const int* in_sizes, int n_in,
                              void* d_out, int out_size, void* d_ws, size_t ws_size,
                              hipStream_t stream) {
    const float* x       = (const float*)d_in[0];
    const float* samples = (const float*)d_in[1];
    const float* W1      = (const float*)d_in[2];
    const float* b1      = (const float*)d_in[3];
    const float* W2      = (const float*)d_in[4];
    const float* b2      = (const float*)d_in[5];
    const float* Wp      = (const float*)d_in[6];
    const float* bp      = (const float*)d_in[7];
    float* out = (float*)d_out;

    char* p = (char*)d_ws;
    float* zpart = (float*)p;                       // 29,360,128 B
    // aliases inside zpart region (dead before fused_mfma writes zpart):
    f16* xsh = (f16*)p;                             // 12,582,912 B  (x || samples, f16)
    f16* h   = (f16*)(p + 12582912);                // 12,582,912 B  (layer-1 out)
    f16* w1t = (f16*)(p + 25165824);                //    524,288 B
    f16* w2t = (f16*)(p + 25690112);                //    524,288 B
    p += (size_t)NSPLIT_ * N_ * CP_ * 4;            // 29,360,128
    f16*  ef  = (f16*)p;   p += (size_t)R_ * D_ * 2;    // 12,582,912
    float* np8 = (float*)p; p += (size_t)8 * R_ * 4;    //    393,216
    f16*  wpT = (f16*)p;   p += (size_t)CP_ * M_ * 2;   //    917,504

    dim3 blk(256);
    prep_all<<<2048, blk, 0, stream>>>(x, samples, W1, W2, Wp, xsh, w1t, w2t, wpT);
    enc_mfma<false><<<dim3(4, R_ / 128), blk, 0, stream>>>(xsh, w1t, b1, h, nullptr);
    enc_mfma<true ><<<dim3(4, R_ / 128), blk, 0, stream>>>(h, w2t, b2, ef, np8);
    fused_mfma<<<dim3(N_ / 128, NSPLIT_), blk, 0, stream>>>(ef, np8, wpT, zpart);
    z_epilogue<<<N_ / 4, blk, 0, stream>>>(zpart, bp, out);
}